// Round 4
// baseline (206.686 us; speedup 1.0000x reference)
//
#include <hip/hip_runtime.h>
#include <hip/hip_bf16.h>
#include <stdint.h>

// y[c,k] = sum_{a,b} E1[k,a] * Xc[c,a,b] * E2[k,b],  Xc = C*x, E = exp(i*angle*g)
// Stage 1 (MFMA): tmp[a, 2k+comp] = A'[a,:] @ B'[:, 2k+comp]
//   A' = [Re(Xc) | Im(Xc)]  (256 x 512)
//   B'[b,2k]=Er, B'[256+b,2k]=-Ei, B'[b,2k+1]=Ei, B'[256+b,2k+1]=Er
// Stage 2 (epilogue): y[c,k] = sum_a E1[k,a] (*) tmp[a,k]  (complex), * w[k%512]
//
// R4: kill the LDS-pipe + lockstep bottleneck identified in R3's counters.
//  - B fragments DIRECT from global into registers, prefetched ONE FULL TILE
//    ahead (double-buffered regs, ~2500 cyc latency cover). B's intra-block
//    reuse is only 2x (wr pair; 2nd hit comes from L1) -> LDS staging bought
//    nothing for B. Halves LDS reads + staging writes + gload_lds count.
//  - NO VMEM WAIT inside the tile body: MFMAs read LDS-A (lgkm) + resident
//    B regs. Only vmcnt(0) is the per-tile __syncthreads, where every
//    outstanding load is a full tile old (R2's vmcnt hazard structurally gone).
//  - 256-thr blocks (4 waves 2Mx2N, wave tile 128x64, acc[8][4]); LDS =
//    2x32KB A dbuf + 1KB -> 2 blocks/CU restores m114 cross-block overlap
//    (the thing R0's 95us had and R3's 1-block/CU lost). No per-phase
//    barriers: independent blocks provide the pipe overlap.
//  - A keeps chunk-XOR swizzle (slot = chunk ^ (row&7)); conflicts were 0.

#define NKTOT 17408
#define NBLK 272    // ktiles of 64 k-values
#define LDA 512
#define LDBT 512

typedef short bf16x8 __attribute__((ext_vector_type(8)));
typedef float f32x4 __attribute__((ext_vector_type(4)));

__device__ __forceinline__ unsigned short f2bf(float f) {
  unsigned int u = __builtin_bit_cast(unsigned int, f);
  u += 0x7FFFu + ((u >> 16) & 1u);
  return (unsigned short)(u >> 16);
}
__device__ __forceinline__ float bf2f(unsigned int lo16) {
  return __builtin_bit_cast(float, lo16 << 16);
}

__device__ __forceinline__ void async_copy16(void* lds, const void* g) {
  __builtin_amdgcn_global_load_lds(
      (const __attribute__((address_space(1))) unsigned int*)g,
      (__attribute__((address_space(3))) unsigned int*)lds, 16, 0, 0);
}

__global__ __launch_bounds__(256) void pack_a(
    const float* __restrict__ input_r, const float* __restrict__ C_r,
    unsigned short* __restrict__ Apack)
{
  int tid = blockIdx.x * 256 + threadIdx.x;  // 0 .. 8*256*256-1
  int b = tid & 255;
  int a = (tid >> 8) & 255;
  int c = tid >> 16;
  float xr = input_r[(a * 256 + b) * 2 + 0];
  float xi = input_r[(a * 256 + b) * 2 + 1];
  size_t ci0 = ((size_t)(c * 256 + a) * 256 + b) * 2;
  float cr = C_r[ci0 + 0];
  float ci = C_r[ci0 + 1];
  float re = cr * xr - ci * xi;
  float im = cr * xi + ci * xr;
  size_t base = (size_t)c * (256 * LDA) + (size_t)a * LDA;
  Apack[base + b] = f2bf(re);
  Apack[base + 256 + b] = f2bf(im);
}

// 4 k per block, 64 lanes per k, 4 consecutive b per lane -> 8B/16B wide stores
__global__ __launch_bounds__(256) void pack_be(
    const float* __restrict__ angle,
    unsigned short* __restrict__ BT, unsigned int* __restrict__ E1tab)
{
  int tid = threadIdx.x;
  int k = blockIdx.x * 4 + (tid >> 6);   // 0..17407
  int b0 = (tid & 63) * 4;               // 0,4,..,252
  float s = angle[k * 2 + 0];
  float t = angle[k * 2 + 1];
  unsigned short c2[4], s2[4], c1[4], s1[4];
#pragma unroll
  for (int j = 0; j < 4; ++j) {
    float g = (float)(b0 + j - 128);
    float sn, cs;
    __sincosf(t * g, &sn, &cs);
    c2[j] = f2bf(cs);
    s2[j] = f2bf(sn);
    __sincosf(s * g, &sn, &cs);
    c1[j] = f2bf(cs);
    s1[j] = f2bf(sn);
  }
  size_t r0 = (size_t)(2 * k) * LDBT;
  ushort4 v;
  v = make_ushort4(c2[0], c2[1], c2[2], c2[3]);
  *(ushort4*)&BT[r0 + b0] = v;
  v = make_ushort4((unsigned short)(s2[0] ^ 0x8000u), (unsigned short)(s2[1] ^ 0x8000u),
                   (unsigned short)(s2[2] ^ 0x8000u), (unsigned short)(s2[3] ^ 0x8000u));
  *(ushort4*)&BT[r0 + 256 + b0] = v;
  v = make_ushort4(s2[0], s2[1], s2[2], s2[3]);
  *(ushort4*)&BT[r0 + LDBT + b0] = v;
  v = make_ushort4(c2[0], c2[1], c2[2], c2[3]);
  *(ushort4*)&BT[r0 + LDBT + 256 + b0] = v;
  uint4 e;
  e.x = (unsigned int)c1[0] | ((unsigned int)s1[0] << 16);
  e.y = (unsigned int)c1[1] | ((unsigned int)s1[1] << 16);
  e.z = (unsigned int)c1[2] | ((unsigned int)s1[2] << 16);
  e.w = (unsigned int)c1[3] | ((unsigned int)s1[3] << 16);
  *(uint4*)&E1tab[k * 256 + b0] = e;
}

// stage A chunk ci (rows ci*8..ci*8+7, 64 elems wide) with chunk-XOR swizzle:
// LDS dest linear (gload_lds requirement), per-lane global source chunk permuted.
__device__ __forceinline__ void stage_chunkA(unsigned short* dst,
    const unsigned short* src_base, int ci, int lr, int lcs, int kk) {
  int row0 = ci * 8;
  async_copy16(&dst[row0 * 64], src_base + (size_t)(row0 + lr) * LDA + kk + lcs);
}

__global__ __launch_bounds__(256, 2) void gemm_fused(
    const unsigned short* __restrict__ Apack,
    const unsigned short* __restrict__ BT,
    const unsigned int* __restrict__ E1tab,
    const float* __restrict__ wvec,
    float* __restrict__ out)
{
  __shared__ unsigned short As[2][256 * 64];  // 2 x 32 KB A double-buffer
  __shared__ float wavecol[2][128];           // 1 KB

  // XCD-aware decode: bx%8 == ktile%8 keeps all 8 c-blocks of one ktile on the
  // same XCD (shared BT/E1 slices served from one L2). 2176 = 34*64, bijective.
  const int bx = blockIdx.x;
  const int c = (bx >> 3) & 7;
  const int ktile = (bx >> 6) * 8 + (bx & 7);   // 0..271
  const int kt0 = ktile * 64;                   // first k-value of this block
  const int tid = threadIdx.x;
  const int w = tid >> 6;       // 0..3
  const int wr = w >> 1;        // 0..1  M-half (rows wr*128..)
  const int wc = w & 1;         // 0..1  N-half (cols wc*64..)
  const int l = tid & 63;
  const int lhi = l >> 4;       // 0..3
  const int llo = l & 15;
  const int lr = l >> 3;                      // staging: row within 8-row chunk
  const int lcs = ((l & 7) ^ lr) * 8;         // staging: swizzled source chunk

  const unsigned short* Abase = Apack + (size_t)c * (256 * LDA);
  // Per-lane B base: col = ktile*128 + wc*64 + fj*16 + llo (BT row), elem
  // lhi*8 + kk + kf*32. Lanes (llo fixed, lhi 0..3) cover 64 contiguous bytes.
  const unsigned short* Bw =
      BT + ((size_t)(ktile * 128) + wc * 64 + llo) * LDBT + lhi * 8;

  // LDS fragment addressing: slot (kf*4+lhi)^(row&7), row = arow0 + m*16
  const int arow0 = wr * 128 + llo;
  const int sl0 = lhi ^ (llo & 7);

  f32x4 acc[8][4];
#pragma unroll
  for (int i = 0; i < 8; ++i)
#pragma unroll
    for (int j = 0; j < 4; ++j) {
      f32x4 z = {0.f, 0.f, 0.f, 0.f};
      acc[i][j] = z;
    }

  bf16x8 bfrag[2][2][4];   // [buf][kf][fj] — all indices compile-time (rule #20)

  // Prologue: B tile 0 into bfrag[0]; stage A tile 0 into As[0] (8 chunks/wave)
#pragma unroll
  for (int kf = 0; kf < 2; ++kf)
#pragma unroll
    for (int fj = 0; fj < 4; ++fj)
      bfrag[0][kf][fj] =
          *(const bf16x8*)(Bw + (size_t)(fj * 16) * LDBT + kf * 32);
#pragma unroll
  for (int i = 0; i < 8; ++i)
    stage_chunkA(&As[0][0], Abase, w * 8 + i, lr, lcs, 0);
  __syncthreads();

#pragma unroll
  for (int t = 0; t < 8; ++t) {
    const int cu = t & 1;
    const int nx = cu ^ 1;
    // Issue next tile's B-frag loads (regs) + A staging (LDS) FIRST; nothing
    // in this tile waits on them — consumed after the tile-end barrier.
    if (t < 7) {
      const int kn = (t + 1) * 64;
#pragma unroll
      for (int kf = 0; kf < 2; ++kf)
#pragma unroll
        for (int fj = 0; fj < 4; ++fj)
          bfrag[nx][kf][fj] =
              *(const bf16x8*)(Bw + (size_t)(fj * 16) * LDBT + kn + kf * 32);
#pragma unroll
      for (int i = 0; i < 8; ++i)
        stage_chunkA(&As[nx][0], Abase, w * 8 + i, lr, lcs, kn);
    }
    __builtin_amdgcn_sched_barrier(0);   // pin prefetch-issue before compute

#pragma unroll
    for (int kf = 0; kf < 2; ++kf) {
      const int soff = (sl0 ^ (kf * 4)) * 8;
      bf16x8 af[4];
      // m-half 0: rows arow0 + 0..63
#pragma unroll
      for (int m = 0; m < 4; ++m)
        af[m] = *(const bf16x8*)&As[cu][(arow0 + m * 16) * 64 + soff];
#pragma unroll
      for (int m = 0; m < 4; ++m)
#pragma unroll
        for (int n = 0; n < 4; ++n)
          acc[m][n] = __builtin_amdgcn_mfma_f32_16x16x32_bf16(
              af[m], bfrag[cu][kf][n], acc[m][n], 0, 0, 0);
      // m-half 1: rows arow0 + 64..127
#pragma unroll
      for (int m = 0; m < 4; ++m)
        af[m] = *(const bf16x8*)&As[cu][(arow0 + 64 + m * 16) * 64 + soff];
#pragma unroll
      for (int m = 0; m < 4; ++m)
#pragma unroll
        for (int n = 0; n < 4; ++n)
          acc[4 + m][n] = __builtin_amdgcn_mfma_f32_16x16x32_bf16(
              af[m], bfrag[cu][kf][n], acc[4 + m][n], 0, 0, 0);
    }
    // Tile end: lgkm+vm drain (everything a full tile old) + buffer swap.
    __syncthreads();
  }

  // Epilogue: y_partial[col] = sum over this wave's 128 a-rows of E1 (*) tmp
  // col = wc*64 + fj*16 + llo (0..127); even col -> Re(tmp), odd -> Im;
  // k = kt0 + col/2
#pragma unroll
  for (int fj = 0; fj < 4; ++fj) {
    const int col = wc * 64 + fj * 16 + llo;
    const int k = kt0 + (col >> 1);
    const float sign = (col & 1) ? 1.f : -1.f;
    float sum = 0.f;
    const unsigned int* e1base = E1tab + (size_t)k * 256 + wr * 128 + lhi * 4;
#pragma unroll
    for (int fi = 0; fi < 8; ++fi) {
      uint4 e4 = *(const uint4*)(e1base + fi * 16);
      unsigned int ev[4] = {e4.x, e4.y, e4.z, e4.w};
#pragma unroll
      for (int r = 0; r < 4; ++r) {
        float v = acc[fi][fj][r];             // this comp at (a, k)
        float p = __shfl_xor(v, 1, 64);       // partner comp at same (a, k)
        float er = bf2f(ev[r] & 0xFFFFu);
        float ei = bf2f(ev[r] >> 16);
        // even col: Re(y) += er*tr - ei*ti ; odd col: Im(y) += er*ti + ei*tr
        sum += er * v + sign * ei * p;
      }
    }
    sum += __shfl_xor(sum, 16, 64);
    sum += __shfl_xor(sum, 32, 64);
    if (lhi == 0) wavecol[wr][col] = sum;
  }
  __syncthreads();
  if (tid < 128) {
    float sv = wavecol[0][tid] + wavecol[1][tid];
    int k = kt0 + (tid >> 1);
    out[((size_t)c * NKTOT + k) * 2 + (tid & 1)] = sv * wvec[k & 511];
  }
}

extern "C" void kernel_launch(void* const* d_in, const int* in_sizes, int n_in,
                              void* d_out, int out_size, void* d_ws, size_t ws_size,
                              hipStream_t stream) {
  const float* input_r = (const float*)d_in[0];  // (256,256,2)
  const float* C_r     = (const float*)d_in[1];  // (8,256,256,2)
  const float* wvec    = (const float*)d_in[2];  // (512,)
  const float* angle   = (const float*)d_in[3];  // (17408,2)
  float* out = (float*)d_out;                    // (8,17408,2)

  // workspace layout: A' (2MB) | B'T (34MB) | E1tab (17MB)  => ~55MB
  unsigned short* Apack = (unsigned short*)d_ws;
  unsigned short* BT    = (unsigned short*)((char*)d_ws + (size_t)2097152);
  unsigned int*   E1tab = (unsigned int*)((char*)d_ws + (size_t)2097152 + 35651584);

  pack_a<<<2048, 256, 0, stream>>>(input_r, C_r, Apack);
  pack_be<<<NKTOT / 4, 256, 0, stream>>>(angle, BT, E1tab);
  gemm_fused<<<8 * NBLK, 256, 0, stream>>>(Apack, BT, E1tab, wvec, out);
}

// Round 5
// 141.862 us; speedup vs baseline: 1.4570x; 1.4570x over previous
//
#include <hip/hip_runtime.h>
#include <hip/hip_bf16.h>
#include <stdint.h>

// y[c,k] = sum_{a,b} E1[k,a] * Xc[c,a,b] * E2[k,b],  Xc = C*x, E = exp(i*angle*g)
//
// R5: FLOP fold via even/odd symmetry of g_b = b-128 (R2/R3/R4 taught that
// restructuring R0's schedule loses; so keep R0's proven 2-barrier loop and
// shrink the work instead).
//   T[a,k] = sum_b Xc[a,b] e^{i t g_b}
//          = sum_{j=0..128} cos(t j) XcC[a,j] + i sin(t j) XcS[a,j]
//   XcC[j] = Xc[128+j]+Xc[128-j] (j=1..127), XcC[0]=Xc[128], XcC[128]=Xc[0]
//   XcS[j] = Xc[128+j]-Xc[128-j] (j=1..127), XcS[128]=-Xc[0]
// Re/Im columns need different folded-A rows; absorb signs into A and stack:
//   A_re = [Re XcC (129) | -Im XcS (128)]  rows 0..255   (a = row)
//   A_im = [Im XcC (129) |  Re XcS (128)]  rows 256..511 (a = row-256)
//   Bcol[k] = [cos(t j) (129) | sin(t j) (128)]  -- ONE B column serves both.
// GEMM: M=512, K=257 pad to 320 (5 x BK=64, zero-padded -> identical loop
// geometry to R0), N=64 k per block. FLOPs 73.0 -> 45.7 GF (0.625x), BT
// 34 -> 11 MB, B-tile reuse 4x (all waves share the 64 cols), epilogue loses
// the shfl_xor(v,1) comp-interleave.
// Epilogue: waves 0,1 hold Tr rows, waves 2,3 Ti; each computes S_r = sum
// E1r*v and S_i = sum E1i*v; combine Re = S_rr - S_ii, Im = S_ri + S_ir.

#define NKTOT 17408
#define NBLK 272    // ktiles of 64 k-values
#define LDK 320     // padded K (257 -> 320 = 5 x 64)

typedef short bf16x8 __attribute__((ext_vector_type(8)));
typedef float f32x4 __attribute__((ext_vector_type(4)));

__device__ __forceinline__ unsigned short f2bf(float f) {
  unsigned int u = __builtin_bit_cast(unsigned int, f);
  u += 0x7FFFu + ((u >> 16) & 1u);
  return (unsigned short)(u >> 16);
}
__device__ __forceinline__ float bf2f(unsigned int lo16) {
  return __builtin_bit_cast(float, lo16 << 16);
}

__device__ __forceinline__ void async_copy16(void* lds, const void* g) {
  __builtin_amdgcn_global_load_lds(
      (const __attribute__((address_space(1))) unsigned int*)g,
      (__attribute__((address_space(3))) unsigned int*)lds, 16, 0, 0);
}

// One block per (c, a): 128 threads, thread j folds pair (128+j, 128-j).
__global__ __launch_bounds__(128) void pack_a(
    const float* __restrict__ input_r, const float* __restrict__ C_r,
    unsigned short* __restrict__ Apack)
{
  const int blk = blockIdx.x;          // 0..2047
  const int a = blk & 255;
  const int c = blk >> 8;
  const int j = threadIdx.x;           // 0..127
  const size_t xbase = (size_t)a * 256;
  const size_t cbase = ((size_t)(c * 256 + a)) * 256;
  unsigned short* Ar = Apack + ((size_t)c * 512 + a) * LDK;        // A_re row
  unsigned short* Ai = Apack + ((size_t)c * 512 + 256 + a) * LDK;  // A_im row
  if (j == 0) {
    // b=128 (g=0) -> cos col 0 ; b=0 (g=-128) -> cos col 128, sin col 256
    float xr = input_r[(xbase + 128) * 2], xi = input_r[(xbase + 128) * 2 + 1];
    float cr = C_r[(cbase + 128) * 2],     ci = C_r[(cbase + 128) * 2 + 1];
    float re0 = cr * xr - ci * xi, im0 = cr * xi + ci * xr;
    Ar[0] = f2bf(re0);  Ai[0] = f2bf(im0);
    xr = input_r[xbase * 2]; xi = input_r[xbase * 2 + 1];
    cr = C_r[cbase * 2];     ci = C_r[cbase * 2 + 1];
    float reb = cr * xr - ci * xi, imb = cr * xi + ci * xr;
    Ar[128] = f2bf(reb);  Ai[128] = f2bf(imb);   // XcC[128] = Xc(b=0)
    Ar[256] = f2bf(imb);                         // -Im(XcS[128]) = +Im Xc(b=0)
    Ai[256] = f2bf(-reb);                        //  Re(XcS[128]) = -Re Xc(b=0)
  } else {
    const int bp = 128 + j, bm = 128 - j;
    float xpr = input_r[(xbase + bp) * 2], xpi = input_r[(xbase + bp) * 2 + 1];
    float cpr = C_r[(cbase + bp) * 2],     cpi = C_r[(cbase + bp) * 2 + 1];
    float pr = cpr * xpr - cpi * xpi, pi = cpr * xpi + cpi * xpr;
    float xmr = input_r[(xbase + bm) * 2], xmi = input_r[(xbase + bm) * 2 + 1];
    float cmr = C_r[(cbase + bm) * 2],     cmi = C_r[(cbase + bm) * 2 + 1];
    float mr = cmr * xmr - cmi * xmi, mi = cmr * xmi + cmi * xmr;
    Ar[j]       = f2bf(pr + mr);        //  Re XcC
    Ai[j]       = f2bf(pi + mi);        //  Im XcC
    Ar[128 + j] = f2bf(mi - pi);        // -Im XcS
    Ai[128 + j] = f2bf(pr - mr);        //  Re XcS
  }
  if (j < 63) {  // zero-pad cols 257..319
    Ar[257 + j] = 0;
    Ai[257 + j] = 0;
  }
}

// One block per k: 256 threads. E1 table unchanged (a-axis not folded);
// folded B row = [cos(t j) 129 | sin(t j) 128 | zeros 63].
__global__ __launch_bounds__(256) void pack_be(
    const float* __restrict__ angle,
    unsigned short* __restrict__ BT, unsigned int* __restrict__ E1tab)
{
  const int k = blockIdx.x;
  const int tid = threadIdx.x;
  const float s = angle[k * 2 + 0];
  const float t = angle[k * 2 + 1];
  float sn, cs;
  // E1[k,a], a = tid
  __sincosf(s * (float)(tid - 128), &sn, &cs);
  E1tab[(size_t)k * 256 + tid] =
      (unsigned int)f2bf(cs) | ((unsigned int)f2bf(sn) << 16);
  unsigned short* Brow = BT + (size_t)k * LDK;
  if (tid <= 128) {
    __sincosf(t * (float)tid, &sn, &cs);
    Brow[tid] = f2bf(cs);
    if (tid >= 1) Brow[128 + tid] = f2bf(sn);
  } else if (tid < 192) {
    Brow[128 + tid] = 0;   // cols 257..319
  }
}

__global__ __launch_bounds__(256, 2) void gemm_fused(
    const unsigned short* __restrict__ Apack,
    const unsigned short* __restrict__ BT,
    const unsigned int* __restrict__ E1tab,
    const float* __restrict__ wvec,
    float* __restrict__ out)
{
  __shared__ unsigned short As[512 * 64];  // 64 KB
  __shared__ unsigned short Bs[64 * 64];   // 8 KB
  __shared__ float scol[4][2][64];         // 2 KB
  // total 74 KB -> 2 blocks/CU (the m114 cross-block overlap R0's 95us had)

  // XCD-aware decode: bx%8 == ktile%8 keeps all 8 c-blocks of one ktile on
  // the same XCD. 2176 = 34*64 -> bijective.
  const int bx = blockIdx.x;
  const int c = (bx >> 3) & 7;
  const int ktile = (bx >> 6) * 8 + (bx & 7);   // 0..271
  const int kt0 = ktile * 64;
  const int tid = threadIdx.x;
  const int w = tid >> 6;       // 0..3: rows w*128..w*128+127 of stacked A
  const int l = tid & 63;
  const int lhi = l >> 4;       // 0..3
  const int llo = l & 15;
  const int lr = l >> 3;                      // staging: row within 8-row chunk
  const int lcs = ((l & 7) ^ lr) * 8;         // staging: swizzled source chunk

  const unsigned short* Abase = Apack + (size_t)c * 512 * LDK;
  const unsigned short* Bbase = BT + (size_t)kt0 * LDK;

  // fragment addressing: slot (kf*4+lhi)^(row&7), stored at [row][slot*8]
  const int arow0 = w * 128 + llo;
  const int sl0 = lhi ^ (llo & 7);

  f32x4 acc[8][4];
#pragma unroll
  for (int i = 0; i < 8; ++i)
#pragma unroll
    for (int j = 0; j < 4; ++j) {
      f32x4 z = {0.f, 0.f, 0.f, 0.f};
      acc[i][j] = z;
    }

  for (int tt = 0; tt < 5; ++tt) {
    const int kk = tt * 64;
    // stage A tile 512x64: 64 chunks of 1KB (8 rows each); wave w does 16
#pragma unroll
    for (int i = 0; i < 16; ++i) {
      int row0 = (w * 16 + i) * 8;
      async_copy16(&As[row0 * 64], Abase + (size_t)(row0 + lr) * LDK + kk + lcs);
    }
    // stage B tile 64x64: 8 chunks; wave w does 2
#pragma unroll
    for (int i = 0; i < 2; ++i) {
      int row0 = (w * 2 + i) * 8;
      async_copy16(&Bs[row0 * 64], Bbase + (size_t)(row0 + lr) * LDK + kk + lcs);
    }
    __syncthreads();
#pragma unroll
    for (int kf = 0; kf < 2; ++kf) {
      const int soff = (sl0 ^ (kf * 4)) * 8;
      bf16x8 bfr[4];
#pragma unroll
      for (int fj = 0; fj < 4; ++fj)
        bfr[fj] = *(const bf16x8*)&Bs[(fj * 16 + llo) * 64 + soff];
      bf16x8 af[8];
#pragma unroll
      for (int fi = 0; fi < 8; ++fi)
        af[fi] = *(const bf16x8*)&As[(arow0 + fi * 16) * 64 + soff];
#pragma unroll
      for (int fi = 0; fi < 8; ++fi)
#pragma unroll
        for (int fj = 0; fj < 4; ++fj)
          acc[fi][fj] = __builtin_amdgcn_mfma_f32_16x16x32_bf16(
              af[fi], bfr[fj], acc[fi][fj], 0, 0, 0);
    }
    __syncthreads();
  }

  // Epilogue: wave w holds T rows (w<2: Tr, a=(w&1)*128+...; w>=2: Ti).
  // Per col (one k each): S_r = sum E1r*v, S_i = sum E1i*v over 128 rows.
  const int ahalf = (w & 1) * 128;
#pragma unroll
  for (int fj = 0; fj < 4; ++fj) {
    const int col = fj * 16 + llo;
    const int k = kt0 + col;
    float sumr = 0.f, sumi = 0.f;
    const unsigned int* e1base = E1tab + (size_t)k * 256 + ahalf + lhi * 4;
#pragma unroll
    for (int fi = 0; fi < 8; ++fi) {
      uint4 e4 = *(const uint4*)(e1base + fi * 16);
      unsigned int ev[4] = {e4.x, e4.y, e4.z, e4.w};
#pragma unroll
      for (int r = 0; r < 4; ++r) {
        float v = acc[fi][fj][r];     // T at (a = ahalf + fi*16 + lhi*4 + r, k)
        sumr += bf2f(ev[r] & 0xFFFFu) * v;
        sumi += bf2f(ev[r] >> 16) * v;
      }
    }
    sumr += __shfl_xor(sumr, 16, 64);
    sumr += __shfl_xor(sumr, 32, 64);
    sumi += __shfl_xor(sumi, 16, 64);
    sumi += __shfl_xor(sumi, 32, 64);
    if (lhi == 0) {
      scol[w][0][col] = sumr;
      scol[w][1][col] = sumi;
    }
  }
  __syncthreads();
  if (tid < 128) {
    const int col = tid >> 1;
    const int comp = tid & 1;
    const int k = kt0 + col;
    // Re = sum E1r*Tr - sum E1i*Ti ; Im = sum E1i*Tr + sum E1r*Ti
    float re = scol[0][0][col] + scol[1][0][col]
             - scol[2][1][col] - scol[3][1][col];
    float im = scol[0][1][col] + scol[1][1][col]
             + scol[2][0][col] + scol[3][0][col];
    float val = comp ? im : re;
    out[((size_t)c * NKTOT + k) * 2 + comp] = val * wvec[k & 511];
  }
}

extern "C" void kernel_launch(void* const* d_in, const int* in_sizes, int n_in,
                              void* d_out, int out_size, void* d_ws, size_t ws_size,
                              hipStream_t stream) {
  const float* input_r = (const float*)d_in[0];  // (256,256,2)
  const float* C_r     = (const float*)d_in[1];  // (8,256,256,2)
  const float* wvec    = (const float*)d_in[2];  // (512,)
  const float* angle   = (const float*)d_in[3];  // (17408,2)
  float* out = (float*)d_out;                    // (8,17408,2)

  // workspace: A'' 8*512*320*2 = 2.62MB | BT 17408*320*2 = 11.1MB |
  //            E1tab 17408*256*4 = 17.8MB  => ~31.6MB
  unsigned short* Apack = (unsigned short*)d_ws;
  unsigned short* BT    = (unsigned short*)((char*)d_ws + (size_t)2621440);
  unsigned int*   E1tab = (unsigned int*)((char*)d_ws + (size_t)2621440 + 11141120);

  pack_a<<<2048, 128, 0, stream>>>(input_r, C_r, Apack);
  pack_be<<<NKTOT, 256, 0, stream>>>(angle, BT, E1tab);
  gemm_fused<<<8 * NBLK, 256, 0, stream>>>(Apack, BT, E1tab, wvec, out);
}